// Round 1
// baseline (1216.574 us; speedup 1.0000x reference)
//
#include <hip/hip_runtime.h>

// MoE top-2 of 8 experts, D=1024, H=4096, 4096 tokens.
// Strategy: gate -> group pairs by expert -> two grouped GEMMs in bf16x3
// split precision (hi/lo bf16, 3 MFMA per K-step => ~fp32 accuracy).

#define NTOK   4096
#define DMODEL 1024
#define HDIM   4096
#define NEXP   8
#define NPAIR  8192
#define LSTR   56   // shorts per LDS row: 32 data + 24 pad (112B: 16B-aligned, ~2-way banks)

typedef __attribute__((ext_vector_type(8))) short short8;
typedef __attribute__((ext_vector_type(4))) float floatx4;

__device__ __forceinline__ short f2bf(float f) {
  unsigned u = __float_as_uint(f);
  u += 0x7FFFu + ((u >> 16) & 1u);          // RNE
  return (short)(u >> 16);
}
__device__ __forceinline__ float bf2f(short s) {
  return __uint_as_float(((unsigned)(unsigned short)s) << 16);
}

// ---------------- gating: 1 wave per token ----------------
__global__ __launch_bounds__(256) void k_gate(
    const float* __restrict__ x, const float* __restrict__ Wg,
    const float* __restrict__ bg, int* __restrict__ counts,
    int* __restrict__ tok_e, float* __restrict__ tok_w) {
  const int token = blockIdx.x * 4 + (threadIdx.x >> 6);
  const int lane = threadIdx.x & 63;
  const float* xr = x + (size_t)token * DMODEL;
  float a[8] = {0.f,0.f,0.f,0.f,0.f,0.f,0.f,0.f};
  for (int d = lane; d < DMODEL; d += 64) {
    const float xv = xr[d];
    const float4 w0 = *reinterpret_cast<const float4*>(Wg + d * 8);
    const float4 w1 = *reinterpret_cast<const float4*>(Wg + d * 8 + 4);
    a[0] += xv * w0.x; a[1] += xv * w0.y; a[2] += xv * w0.z; a[3] += xv * w0.w;
    a[4] += xv * w1.x; a[5] += xv * w1.y; a[6] += xv * w1.z; a[7] += xv * w1.w;
  }
  #pragma unroll
  for (int e = 0; e < 8; ++e)
    #pragma unroll
    for (int off = 32; off; off >>= 1)
      a[e] += __shfl_xor(a[e], off);
  if (lane == 0) {
    float l[8];
    #pragma unroll
    for (int e = 0; e < 8; ++e) l[e] = a[e] + bg[e];
    int e0 = 0;
    #pragma unroll
    for (int e = 1; e < 8; ++e) if (l[e] > l[e0]) e0 = e;
    int e1 = (e0 == 0) ? 1 : 0;
    #pragma unroll
    for (int e = 0; e < 8; ++e) if (e != e0 && l[e] > l[e1]) e1 = e;
    // top-2 renormalized softmax == sigmoid of logit gap (Z cancels)
    const float p  = expf(l[e1] - l[e0]);
    const float w0 = 1.0f / (1.0f + p);
    const float w1 = p * w0;
    tok_e[token * 2]     = e0;  tok_e[token * 2 + 1] = e1;
    tok_w[token * 2]     = w0;  tok_w[token * 2 + 1] = w1;
    atomicAdd(&counts[e0], 1);  atomicAdd(&counts[e1], 1);
  }
}

// ---------------- scatter pairs grouped by expert ----------------
__global__ __launch_bounds__(256) void k_scatter(
    const int* __restrict__ counts, int* __restrict__ bases,
    const int* __restrict__ tok_e, const float* __restrict__ tok_w,
    int* __restrict__ pair_token, float* __restrict__ pair_w) {
  __shared__ int sbase[8];
  __shared__ int scur[8];
  const int tid = threadIdx.x;
  if (tid < 8) {
    int b = 0;
    for (int i = 0; i < tid; ++i) b += counts[i];
    sbase[tid] = b; bases[tid] = b; scur[tid] = 0;
  }
  __syncthreads();
  for (int i = tid; i < NPAIR; i += 256) {
    const int e = tok_e[i];
    const int slot = sbase[e] + atomicAdd(&scur[e], 1);
    pair_token[slot] = i >> 1;
    pair_w[slot] = tok_w[i];
  }
}

// ---------------- pass A: h = gelu(Xg * W1_e + b1_e) ----------------
__global__ __launch_bounds__(256, 2) void k_ffn1(
    const float* __restrict__ x, const float* __restrict__ W1,
    const float* __restrict__ b1, const int* __restrict__ counts,
    const int* __restrict__ bases, const int* __restrict__ pair_token,
    float* __restrict__ h) {
  __shared__ short Ah[128 * LSTR], Al[128 * LSTR], Bh[128 * LSTR], Bl[128 * LSTR];
  const int bid = blockIdx.x;
  const int e   = bid >> 9;          // / (16 * 32)
  const int rem = bid & 511;
  const int mt0 = rem >> 5;
  const int nt  = rem & 31;
  const int n_e  = counts[e];
  const int base = bases[e];

  const int tid  = threadIdx.x;
  const int lane = tid & 63;
  const int wid  = tid >> 6;
  const int wr = wid >> 1, wc = wid & 1;
  const int fr  = lane & 15;
  const int fks = (lane >> 4) << 3;

  const int ar  = tid >> 1;           // A stage: row
  const int ac  = (tid & 1) << 4;     // A stage: col base (16 floats)
  const int bn  = tid & 127;          // B stage: output col (n)
  const int bk0 = (tid >> 7) << 4;    // B stage: k base (16 rows)

  const float* __restrict__ Wmat  = W1 + (size_t)e * DMODEL * HDIM;
  const int ncol = nt * 128 + bn;
  const float* __restrict__ bSrc0 = Wmat + (size_t)bk0 * HDIM + ncol;

  float aReg[16], bReg[16];

  for (int mt = mt0; mt * 128 < n_e; mt += 16) {
    const int row0 = base + mt * 128;
    int rows_in = n_e - mt * 128; if (rows_in > 128) rows_in = 128;
    const int tokA = pair_token[row0 + ((ar < rows_in) ? ar : 0)];
    const float* __restrict__ aSrc = x + (size_t)tokA * DMODEL + ac;

    floatx4 acc[4][4];
    #pragma unroll
    for (int m = 0; m < 4; ++m)
      #pragma unroll
      for (int n = 0; n < 4; ++n) acc[m][n] = floatx4{0.f, 0.f, 0.f, 0.f};

    auto LOADA = [&](int kt) {
      const float* p = aSrc + kt * 32;
      #pragma unroll
      for (int i = 0; i < 4; ++i) {
        const float4 v = *reinterpret_cast<const float4*>(p + i * 4);
        aReg[i*4+0] = v.x; aReg[i*4+1] = v.y; aReg[i*4+2] = v.z; aReg[i*4+3] = v.w;
      }
    };
    auto LOADB = [&](int kt) {
      const float* p = bSrc0 + (size_t)kt * 32 * HDIM;
      #pragma unroll
      for (int j = 0; j < 16; ++j) bReg[j] = p[(size_t)j * HDIM];
    };

    LOADA(0); LOADB(0);
    #pragma unroll 1
    for (int kt = 0; kt < DMODEL / 32; ++kt) {
      __syncthreads();
      #pragma unroll
      for (int half = 0; half < 2; ++half) {           // convert + LDS write
        short8 vh, vl, wh, wl;
        #pragma unroll
        for (int j = 0; j < 8; ++j) {
          const float fa = aReg[half*8+j];
          const short ha = f2bf(fa);
          vh[j] = ha; vl[j] = f2bf(fa - bf2f(ha));
          const float fb = bReg[half*8+j];
          const short hb = f2bf(fb);
          wh[j] = hb; wl[j] = f2bf(fb - bf2f(hb));
        }
        *reinterpret_cast<short8*>(&Ah[ar*LSTR + ac + half*8]) = vh;
        *reinterpret_cast<short8*>(&Al[ar*LSTR + ac + half*8]) = vl;
        *reinterpret_cast<short8*>(&Bh[bn*LSTR + bk0 + half*8]) = wh;
        *reinterpret_cast<short8*>(&Bl[bn*LSTR + bk0 + half*8]) = wl;
      }
      __syncthreads();
      if (kt + 1 < DMODEL / 32) { LOADA(kt + 1); LOADB(kt + 1); }  // hide HBM under MFMA
      short8 fa[4], fal[4], fb[4], fbl[4];
      #pragma unroll
      for (int m = 0; m < 4; ++m) {
        const int r = (wr*64 + m*16 + fr) * LSTR + fks;
        fa[m]  = *reinterpret_cast<const short8*>(&Ah[r]);
        fal[m] = *reinterpret_cast<const short8*>(&Al[r]);
      }
      #pragma unroll
      for (int n = 0; n < 4; ++n) {
        const int c = (wc*64 + n*16 + fr) * LSTR + fks;
        fb[n]  = *reinterpret_cast<const short8*>(&Bh[c]);
        fbl[n] = *reinterpret_cast<const short8*>(&Bl[c]);
      }
      #pragma unroll
      for (int m = 0; m < 4; ++m)
        #pragma unroll
        for (int n = 0; n < 4; ++n) {
          acc[m][n] = __builtin_amdgcn_mfma_f32_16x16x32_bf16(fa[m],  fb[n],  acc[m][n], 0, 0, 0);
          acc[m][n] = __builtin_amdgcn_mfma_f32_16x16x32_bf16(fa[m],  fbl[n], acc[m][n], 0, 0, 0);
          acc[m][n] = __builtin_amdgcn_mfma_f32_16x16x32_bf16(fal[m], fb[n],  acc[m][n], 0, 0, 0);
        }
    }
    const int jr = (lane >> 4) << 2;
    #pragma unroll
    for (int m = 0; m < 4; ++m)
      #pragma unroll
      for (int j = 0; j < 4; ++j) {
        const int rl = wr*64 + m*16 + jr + j;
        if (rl < rows_in) {
          float* hp = h + (size_t)(row0 + rl) * HDIM;
          #pragma unroll
          for (int n = 0; n < 4; ++n) {
            const int col = nt*128 + wc*64 + n*16 + fr;
            float v = acc[m][n][j] + b1[e * HDIM + col];
            v = 0.5f * v * (1.0f + erff(v * 0.70710678118654752440f));  // exact gelu
            hp[col] = v;
          }
        }
      }
  }
}

// ---------------- pass B: out += g * (h * W2_e + b2_e) ----------------
__global__ __launch_bounds__(256, 2) void k_ffn2(
    const float* __restrict__ h, const float* __restrict__ W2,
    const float* __restrict__ b2, const int* __restrict__ counts,
    const int* __restrict__ bases, const int* __restrict__ pair_token,
    const float* __restrict__ pair_w, float* __restrict__ out) {
  __shared__ short Ah[128 * LSTR], Al[128 * LSTR], Bh[128 * LSTR], Bl[128 * LSTR];
  const int bid = blockIdx.x;
  const int e   = bid >> 7;          // / (16 * 8)
  const int rem = bid & 127;
  const int mt0 = rem >> 3;
  const int nt  = rem & 7;
  const int n_e  = counts[e];
  const int base = bases[e];

  const int tid  = threadIdx.x;
  const int lane = tid & 63;
  const int wid  = tid >> 6;
  const int wr = wid >> 1, wc = wid & 1;
  const int fr  = lane & 15;
  const int fks = (lane >> 4) << 3;

  const int ar  = tid >> 1;
  const int ac  = (tid & 1) << 4;
  const int bn  = tid & 127;
  const int bk0 = (tid >> 7) << 4;

  const float* __restrict__ Wmat  = W2 + (size_t)e * HDIM * DMODEL;
  const int ncol = nt * 128 + bn;
  const float* __restrict__ bSrc0 = Wmat + (size_t)bk0 * DMODEL + ncol;

  float aReg[16], bReg[16];

  for (int mt = mt0; mt * 128 < n_e; mt += 16) {
    const int row0 = base + mt * 128;
    int rows_in = n_e - mt * 128; if (rows_in > 128) rows_in = 128;
    const int slotA = row0 + ((ar < rows_in) ? ar : 0);
    const float* __restrict__ aSrc = h + (size_t)slotA * HDIM + ac;

    floatx4 acc[4][4];
    #pragma unroll
    for (int m = 0; m < 4; ++m)
      #pragma unroll
      for (int n = 0; n < 4; ++n) acc[m][n] = floatx4{0.f, 0.f, 0.f, 0.f};

    auto LOADA = [&](int kt) {
      const float* p = aSrc + kt * 32;
      #pragma unroll
      for (int i = 0; i < 4; ++i) {
        const float4 v = *reinterpret_cast<const float4*>(p + i * 4);
        aReg[i*4+0] = v.x; aReg[i*4+1] = v.y; aReg[i*4+2] = v.z; aReg[i*4+3] = v.w;
      }
    };
    auto LOADB = [&](int kt) {
      const float* p = bSrc0 + (size_t)kt * 32 * DMODEL;
      #pragma unroll
      for (int j = 0; j < 16; ++j) bReg[j] = p[(size_t)j * DMODEL];
    };

    LOADA(0); LOADB(0);
    #pragma unroll 1
    for (int kt = 0; kt < HDIM / 32; ++kt) {
      __syncthreads();
      #pragma unroll
      for (int half = 0; half < 2; ++half) {
        short8 vh, vl, wh, wl;
        #pragma unroll
        for (int j = 0; j < 8; ++j) {
          const float fa = aReg[half*8+j];
          const short ha = f2bf(fa);
          vh[j] = ha; vl[j] = f2bf(fa - bf2f(ha));
          const float fb = bReg[half*8+j];
          const short hb = f2bf(fb);
          wh[j] = hb; wl[j] = f2bf(fb - bf2f(hb));
        }
        *reinterpret_cast<short8*>(&Ah[ar*LSTR + ac + half*8]) = vh;
        *reinterpret_cast<short8*>(&Al[ar*LSTR + ac + half*8]) = vl;
        *reinterpret_cast<short8*>(&Bh[bn*LSTR + bk0 + half*8]) = wh;
        *reinterpret_cast<short8*>(&Bl[bn*LSTR + bk0 + half*8]) = wl;
      }
      __syncthreads();
      if (kt + 1 < HDIM / 32) { LOADA(kt + 1); LOADB(kt + 1); }
      short8 fa[4], fal[4], fb[4], fbl[4];
      #pragma unroll
      for (int m = 0; m < 4; ++m) {
        const int r = (wr*64 + m*16 + fr) * LSTR + fks;
        fa[m]  = *reinterpret_cast<const short8*>(&Ah[r]);
        fal[m] = *reinterpret_cast<const short8*>(&Al[r]);
      }
      #pragma unroll
      for (int n = 0; n < 4; ++n) {
        const int c = (wc*64 + n*16 + fr) * LSTR + fks;
        fb[n]  = *reinterpret_cast<const short8*>(&Bh[c]);
        fbl[n] = *reinterpret_cast<const short8*>(&Bl[c]);
      }
      #pragma unroll
      for (int m = 0; m < 4; ++m)
        #pragma unroll
        for (int n = 0; n < 4; ++n) {
          acc[m][n] = __builtin_amdgcn_mfma_f32_16x16x32_bf16(fa[m],  fb[n],  acc[m][n], 0, 0, 0);
          acc[m][n] = __builtin_amdgcn_mfma_f32_16x16x32_bf16(fa[m],  fbl[n], acc[m][n], 0, 0, 0);
          acc[m][n] = __builtin_amdgcn_mfma_f32_16x16x32_bf16(fal[m], fb[n],  acc[m][n], 0, 0, 0);
        }
    }
    const int jr = (lane >> 4) << 2;
    #pragma unroll
    for (int m = 0; m < 4; ++m)
      #pragma unroll
      for (int j = 0; j < 4; ++j) {
        const int rl = wr*64 + m*16 + jr + j;
        if (rl < rows_in) {
          const int slot = row0 + rl;
          const int token = pair_token[slot];
          const float w = pair_w[slot];
          float* op = out + (size_t)token * DMODEL;
          #pragma unroll
          for (int n = 0; n < 4; ++n) {
            const int col = nt*128 + wc*64 + n*16 + fr;
            atomicAdd(&op[col], w * (acc[m][n][j] + b2[e * DMODEL + col]));
          }
        }
      }
  }
}

extern "C" void kernel_launch(void* const* d_in, const int* in_sizes, int n_in,
                              void* d_out, int out_size, void* d_ws, size_t ws_size,
                              hipStream_t stream) {
  const float* x  = (const float*)d_in[0];
  const float* Wg = (const float*)d_in[1];
  const float* bg = (const float*)d_in[2];
  const float* W1 = (const float*)d_in[3];
  const float* b1 = (const float*)d_in[4];
  const float* W2 = (const float*)d_in[5];
  const float* b2 = (const float*)d_in[6];
  float* out = (float*)d_out;

  char* ws = (char*)d_ws;
  int*   counts     = (int*)(ws + 0);
  int*   bases      = (int*)(ws + 64);
  int*   tok_e      = (int*)(ws + 256);
  float* tok_w      = (float*)(ws + 256 + 32768);
  int*   pair_token = (int*)(ws + 256 + 65536);
  float* pair_w     = (float*)(ws + 256 + 98304);
  float* h          = (float*)(ws + 262144);   // 8192 x 4096 fp32 = 134.2 MB

  hipMemsetAsync(counts, 0, 64, stream);
  hipMemsetAsync(d_out, 0, (size_t)out_size * sizeof(float), stream);
  k_gate<<<NTOK / 4, 256, 0, stream>>>(x, Wg, bg, counts, tok_e, tok_w);
  k_scatter<<<1, 256, 0, stream>>>(counts, bases, tok_e, tok_w, pair_token, pair_w);
  k_ffn1<<<NEXP * 16 * (HDIM / 128), 256, 0, stream>>>(x, W1, b1, counts, bases, pair_token, h);
  k_ffn2<<<NEXP * 16 * (DMODEL / 128), 256, 0, stream>>>(h, W2, b2, counts, bases, pair_token, pair_w, out);
}